// Round 6
// baseline (158.901 us; speedup 1.0000x reference)
//
#include <hip/hip_runtime.h>
#include <hip/hip_cooperative_groups.h>

namespace cg = cooperative_groups;

#define BATCH 384
#define DIM   1024
#define MARGIN_F 0.5f
#define EPS_F 1e-16f
#define N2 (BATCH * BATCH)
#define NTILE 12          // 384/32 tile grid
#define NUT   78          // upper-triangle tile count (12*13/2)
#define SPLIT 8           // K slices
#define KSLICE (DIM / SPLIT)
#define GRID_BLKS (NUT * SPLIT)   // 624

// ---------------------------------------------------------------------------
// One cooperative kernel, three phases separated by grid.sync().
// Phase 1 (all 624 blocks): upper-triangle split-K squared-distance tiles,
//   mirror-stored (bit-exact symmetry), diff form (exact 0 diagonal).
// Phase 2 (blocks 0..383): per-anchor triplet reduction -> part[].
// Phase 3 (block 0, wave 0): double-precision finalize -> out[0..2].
// All phase bodies are verbatim from the round-5 kernels; no fp atomics.
// ---------------------------------------------------------------------------
__global__ __launch_bounds__(256) void fused_kernel(const float* __restrict__ E,
                                                    const int* __restrict__ labels,
                                                    float* __restrict__ dpart,
                                                    float* __restrict__ part,
                                                    float* __restrict__ out) {
    __shared__ float As[32][33];
    __shared__ float Bs[32][33];
    __shared__ float drow[BATCH];
    __shared__ int   lab[BATCH];
    __shared__ int   plist[BATCH];
    __shared__ int   npos_s;
    __shared__ float ssum[4];
    __shared__ int   spos[4];
    __shared__ int   sval[4];

    cg::grid_group grid = cg::this_grid();
    const int t = threadIdx.x;

    // ---------------- phase 1: distance tiles ----------------
    {
        const int bid = blockIdx.x;
        const int z   = bid / NUT;       // 0..SPLIT-1
        int tt        = bid % NUT;       // upper-tri tile index
        int by = 0;
        while (tt >= NTILE - by) { tt -= NTILE - by; ++by; }
        const int bx = by + tt;          // bx >= by

        const int tx = t & 15;
        const int ty = t >> 4;
        const int rb = by * 32;
        const int cb = bx * 32;
        const int kb = z * KSLICE;

        float acc00 = 0.f, acc01 = 0.f, acc10 = 0.f, acc11 = 0.f;

        const int lr = t >> 3;           // 0..31 row within tile
        const int lc = (t & 7) * 4;      // 0,4,...,28

        for (int k0 = 0; k0 < KSLICE; k0 += 32) {
            float4 av = *(const float4*)&E[(size_t)(rb + lr) * DIM + kb + k0 + lc];
            float4 bv = *(const float4*)&E[(size_t)(cb + lr) * DIM + kb + k0 + lc];
            As[lr][lc + 0] = av.x; As[lr][lc + 1] = av.y;
            As[lr][lc + 2] = av.z; As[lr][lc + 3] = av.w;
            Bs[lr][lc + 0] = bv.x; Bs[lr][lc + 1] = bv.y;
            Bs[lr][lc + 2] = bv.z; Bs[lr][lc + 3] = bv.w;
            __syncthreads();

#pragma unroll
            for (int k = 0; k < 32; ++k) {
                float a0 = As[ty * 2 + 0][k];
                float a1 = As[ty * 2 + 1][k];
                float b0 = Bs[tx * 2 + 0][k];
                float b1 = Bs[tx * 2 + 1][k];
                float d;
                d = a0 - b0; acc00 += d * d;
                d = a0 - b1; acc01 += d * d;
                d = a1 - b0; acc10 += d * d;
                d = a1 - b1; acc11 += d * d;
            }
            __syncthreads();
        }

        float* dst = dpart + (size_t)z * N2;
        const int r0 = rb + ty * 2, c0 = cb + tx * 2;
        dst[(size_t)(r0 + 0) * BATCH + c0 + 0] = acc00;
        dst[(size_t)(r0 + 0) * BATCH + c0 + 1] = acc01;
        dst[(size_t)(r0 + 1) * BATCH + c0 + 0] = acc10;
        dst[(size_t)(r0 + 1) * BATCH + c0 + 1] = acc11;

        if (bx != by) {   // mirror store (transposed); bit-identical values
            dst[(size_t)(c0 + 0) * BATCH + r0 + 0] = acc00;
            dst[(size_t)(c0 + 1) * BATCH + r0 + 0] = acc01;
            dst[(size_t)(c0 + 0) * BATCH + r0 + 1] = acc10;
            dst[(size_t)(c0 + 1) * BATCH + r0 + 1] = acc11;
        }
    }

    grid.sync();

    // ---------------- phase 2: per-anchor triplet reduction ----------------
    if (blockIdx.x < BATCH) {
        const int a = blockIdx.x;

        for (int i = t; i < BATCH; i += 256) {
            float s = 0.f;
#pragma unroll
            for (int z = 0; z < SPLIT; ++z)
                s += dpart[(size_t)z * N2 + (size_t)a * BATCH + i];
            drow[i] = s > 0.f ? sqrtf(s) : 0.f;
            lab[i]  = labels[i];
        }
        __syncthreads();

        const int la = lab[a];

        if (t < 64) {   // deterministic positives-list build on wave 0
            int cnt = 0;
#pragma unroll
            for (int c = 0; c < BATCH; c += 64) {
                const int i = c + t;
                const bool f = (lab[i] == la) && (i != a);
                const unsigned long long m = __ballot(f);
                if (f) {
                    const int off = __popcll(m & ((1ull << t) - 1ull));
                    plist[cnt + off] = i;
                }
                cnt += __popcll(m);
            }
            if (t == 0) npos_s = cnt;
        }
        __syncthreads();

        const int npos = npos_s;
        float sum = 0.f;
        int   pos = 0, valid = 0;

        for (int n = t; n < BATCH; n += 256) {
            if (lab[n] != la) {
                const float dan = drow[n];
                valid += npos;
                for (int q = 0; q < npos; ++q) {
                    float tl = drow[plist[q]] - dan + MARGIN_F;
                    if (tl > EPS_F) { sum += tl; ++pos; }
                }
            }
        }

#pragma unroll
        for (int off = 32; off > 0; off >>= 1) {
            sum   += __shfl_down(sum, off);
            pos   += __shfl_down(pos, off);
            valid += __shfl_down(valid, off);
        }
        const int wave = t >> 6, lane = t & 63;
        if (lane == 0) { ssum[wave] = sum; spos[wave] = pos; sval[wave] = valid; }
        __syncthreads();

        if (t == 0) {
            float s = 0.f; int p2 = 0, v = 0;
#pragma unroll
            for (int w = 0; w < 4; ++w) { s += ssum[w]; p2 += spos[w]; v += sval[w]; }
            part[a]             = s;
            part[BATCH + a]     = (float)p2;
            part[2 * BATCH + a] = (float)v;
        }
    }

    grid.sync();

    // ---------------- phase 3: finalize (block 0, wave 0) ----------------
    if (blockIdx.x == 0 && t < 64) {
        const int lane = t;
        double s = 0.0, p = 0.0, v = 0.0;
#pragma unroll
        for (int c = 0; c < BATCH; c += 64) {
            s += (double)part[c + lane];
            p += (double)part[BATCH + c + lane];
            v += (double)part[2 * BATCH + c + lane];
        }
#pragma unroll
        for (int off = 32; off > 0; off >>= 1) {
            s += __shfl_down(s, off);
            p += __shfl_down(p, off);
            v += __shfl_down(v, off);
        }
        if (lane == 0) {
            out[0] = (float)(s / (p + 1e-16));
            out[1] = (float)p;
            out[2] = (float)v;
        }
    }
}

extern "C" void kernel_launch(void* const* d_in, const int* in_sizes, int n_in,
                              void* d_out, int out_size, void* d_ws, size_t ws_size,
                              hipStream_t stream) {
    const int*   labels = (const int*)d_in[0];
    const float* E      = (const float*)d_in[1];
    float* out = (float*)d_out;

    // ws layout: [part @0: 3*384 floats][dpart @8192: SPLIT * N2 floats]
    float* part  = (float*)d_ws;
    float* dpart = (float*)((char*)d_ws + 8192);

    void* args[] = {(void*)&E, (void*)&labels, (void*)&dpart, (void*)&part, (void*)&out};
    hipLaunchCooperativeKernel((const void*)fused_kernel,
                               dim3(GRID_BLKS), dim3(256), args, 0, stream);
}

// Round 7
// 22.643 us; speedup vs baseline: 7.0176x; 7.0176x over previous
//
#include <hip/hip_runtime.h>

#define BATCH 384
#define DIM   1024
#define MARGIN_F 0.5f
#define EPS_F 1e-16f
#define N2 (BATCH * BATCH)

// ---------------------------------------------------------------------------
// Kernel 1: split-K partial gram matrix, UPPER-TRIANGLE 32x32 tiles.
// dot_z[i][j] = sum_{k in slice z} E[i][k]*E[j][k]  -> 1 FMA per output*k
// (diff form costs 2 VALU). Mirror store is exact (a.b == b.a bitwise).
// Diagonal blocks write dot_ii partials to compact ddiag[z][i] so the
// consumer reconstructs d^2 = da + di - 2*dot with an EXACT 0.0 diagonal.
// 2x2 strided micro-tile (rows ty,ty+16 x cols tx,tx+16), float4 LDS reads,
// [32][36] pad (16B-aligned rows, <=2-way banking). Structure = round 5.
// ---------------------------------------------------------------------------
__global__ __launch_bounds__(256) void dist_kernel(const float* __restrict__ E,
                                                   float* __restrict__ dpart,
                                                   float* __restrict__ ddiag,
                                                   int kslice) {
    const int bx = blockIdx.x, by = blockIdx.y;
    if (bx < by) return;   // triangle: only cb >= rb tiles do work

    __shared__ float As[32][36];
    __shared__ float Bs[32][36];

    const int tx = threadIdx.x & 15;
    const int ty = threadIdx.x >> 4;
    const int rb = by * 32;
    const int cb = bx * 32;
    const int kb = blockIdx.z * kslice;

    float acc00 = 0.f, acc01 = 0.f, acc10 = 0.f, acc11 = 0.f;

    const int lr = threadIdx.x >> 3;        // 0..31 row within tile
    const int lc = (threadIdx.x & 7) * 4;   // 0,4,...,28

    for (int k0 = 0; k0 < kslice; k0 += 32) {
        *(float4*)&As[lr][lc] = *(const float4*)&E[(size_t)(rb + lr) * DIM + kb + k0 + lc];
        *(float4*)&Bs[lr][lc] = *(const float4*)&E[(size_t)(cb + lr) * DIM + kb + k0 + lc];
        __syncthreads();

#pragma unroll
        for (int k = 0; k < 32; k += 4) {
            float4 a0 = *(const float4*)&As[ty][k];
            float4 a1 = *(const float4*)&As[ty + 16][k];
            float4 b0 = *(const float4*)&Bs[tx][k];
            float4 b1 = *(const float4*)&Bs[tx + 16][k];
            acc00 += a0.x * b0.x + a0.y * b0.y + a0.z * b0.z + a0.w * b0.w;
            acc01 += a0.x * b1.x + a0.y * b1.y + a0.z * b1.z + a0.w * b1.w;
            acc10 += a1.x * b0.x + a1.y * b0.y + a1.z * b0.z + a1.w * b0.w;
            acc11 += a1.x * b1.x + a1.y * b1.y + a1.z * b1.z + a1.w * b1.w;
        }
        __syncthreads();
    }

    float* dst = dpart + (size_t)blockIdx.z * N2;
    const int r0 = rb + ty, r1 = rb + ty + 16;
    const int c0 = cb + tx, c1 = cb + tx + 16;
    dst[(size_t)r0 * BATCH + c0] = acc00;
    dst[(size_t)r0 * BATCH + c1] = acc01;
    dst[(size_t)r1 * BATCH + c0] = acc10;
    dst[(size_t)r1 * BATCH + c1] = acc11;

    if (bx != by) {   // mirror store (transposed); bit-identical values
        dst[(size_t)c0 * BATCH + r0] = acc00;
        dst[(size_t)c1 * BATCH + r0] = acc01;
        dst[(size_t)c0 * BATCH + r1] = acc10;
        dst[(size_t)c1 * BATCH + r1] = acc11;
    }

    if (bx == by && tx == ty) {   // compact diagonal partials
        ddiag[blockIdx.z * BATCH + r0] = acc00;
        ddiag[blockIdx.z * BATCH + r1] = acc11;
    }
}

// ---------------------------------------------------------------------------
// Kernel 2: per-anchor triplet reduction (round-5 structure; z-loops fully
// unrolled via template). drow[i] = sqrt(da + di - 2*dot_ai); exact 0 at i==a.
// ---------------------------------------------------------------------------
template <int NS>
__global__ __launch_bounds__(256) void triplet_kernel(const float* __restrict__ dpart,
                                                      const float* __restrict__ ddiag,
                                                      const int* __restrict__ labels,
                                                      float* __restrict__ part) {
    __shared__ float drow[BATCH];
    __shared__ int   lab[BATCH];
    __shared__ int   plist[BATCH];
    __shared__ int   npos_s;
    __shared__ float ssum[4];
    __shared__ int   spos[4];
    __shared__ int   sval[4];

    const int t = threadIdx.x;
    const int a = blockIdx.x;

    float da = 0.f;
#pragma unroll
    for (int z = 0; z < NS; ++z) da += ddiag[z * BATCH + a];

    for (int i = t; i < BATCH; i += 256) {
        float row = 0.f, di = 0.f;
#pragma unroll
        for (int z = 0; z < NS; ++z) {
            row += dpart[(size_t)z * N2 + (size_t)a * BATCH + i];
            di  += ddiag[z * BATCH + i];
        }
        const float s = da + di - 2.f * row;   // exactly 0.0 at i==a
        drow[i] = s > 0.f ? sqrtf(s) : 0.f;
        lab[i]  = labels[i];
    }
    __syncthreads();

    const int la = lab[a];

    // deterministic positives-list build on wave 0
    if (t < 64) {
        int cnt = 0;
#pragma unroll
        for (int c = 0; c < BATCH; c += 64) {
            const int i = c + t;
            const bool f = (lab[i] == la) && (i != a);
            const unsigned long long m = __ballot(f);
            if (f) {
                const int off = __popcll(m & ((1ull << t) - 1ull));
                plist[cnt + off] = i;
            }
            cnt += __popcll(m);
        }
        if (t == 0) npos_s = cnt;
    }
    __syncthreads();

    const int npos = npos_s;
    float sum = 0.f;
    int   pos = 0, valid = 0;

    for (int n = t; n < BATCH; n += 256) {
        if (lab[n] != la) {
            const float dan = drow[n];
            valid += npos;
            for (int q = 0; q < npos; ++q) {
                float tl = drow[plist[q]] - dan + MARGIN_F;
                if (tl > EPS_F) { sum += tl; ++pos; }
            }
        }
    }

#pragma unroll
    for (int off = 32; off > 0; off >>= 1) {
        sum   += __shfl_down(sum, off);
        pos   += __shfl_down(pos, off);
        valid += __shfl_down(valid, off);
    }
    const int wave = t >> 6, lane = t & 63;
    if (lane == 0) { ssum[wave] = sum; spos[wave] = pos; sval[wave] = valid; }
    __syncthreads();

    if (t == 0) {
        float s = 0.f; int p2 = 0, v = 0;
#pragma unroll
        for (int w = 0; w < 4; ++w) { s += ssum[w]; p2 += spos[w]; v += sval[w]; }
        part[a]             = s;
        part[BATCH + a]     = (float)p2;
        part[2 * BATCH + a] = (float)v;
    }
}

// ---------------------------------------------------------------------------
// Kernel 3: one-wave finalize. Double accumulation of 384 partials.
// ---------------------------------------------------------------------------
__global__ __launch_bounds__(64) void finalize_kernel(const float* __restrict__ part,
                                                      float* __restrict__ out) {
    const int lane = threadIdx.x;
    double s = 0.0, p = 0.0, v = 0.0;
#pragma unroll
    for (int c = 0; c < BATCH; c += 64) {
        s += (double)part[c + lane];
        p += (double)part[BATCH + c + lane];
        v += (double)part[2 * BATCH + c + lane];
    }
#pragma unroll
    for (int off = 32; off > 0; off >>= 1) {
        s += __shfl_down(s, off);
        p += __shfl_down(p, off);
        v += __shfl_down(v, off);
    }
    if (lane == 0) {
        out[0] = (float)(s / (p + 1e-16));
        out[1] = (float)p;
        out[2] = (float)v;
    }
}

extern "C" void kernel_launch(void* const* d_in, const int* in_sizes, int n_in,
                              void* d_out, int out_size, void* d_ws, size_t ws_size,
                              hipStream_t stream) {
    const int*   labels = (const int*)d_in[0];
    const float* E      = (const float*)d_in[1];
    float* out = (float*)d_out;

    // ws layout: [part @0: 3*384 f][ddiag @8192: S*384 f][dpart @24576: S*N2 f]
    float* part  = (float*)d_ws;
    float* ddiag = (float*)((char*)d_ws + 8192);
    float* dpart = (float*)((char*)d_ws + 24576);

    int S = 8;
    while (S > 1 && 24576 + (size_t)S * N2 * sizeof(float) > ws_size) S >>= 1;
    const int kslice = DIM / S;

    dim3 grid(BATCH / 32, BATCH / 32, S);
    dist_kernel<<<grid, 256, 0, stream>>>(E, dpart, ddiag, kslice);

    switch (S) {
        case 8: triplet_kernel<8><<<BATCH, 256, 0, stream>>>(dpart, ddiag, labels, part); break;
        case 4: triplet_kernel<4><<<BATCH, 256, 0, stream>>>(dpart, ddiag, labels, part); break;
        case 2: triplet_kernel<2><<<BATCH, 256, 0, stream>>>(dpart, ddiag, labels, part); break;
        default: triplet_kernel<1><<<BATCH, 256, 0, stream>>>(dpart, ddiag, labels, part); break;
    }
    finalize_kernel<<<1, 64, 0, stream>>>(part, out);
}